// Round 6
// baseline (17278.055 us; speedup 1.0000x reference)
//
#include <hip/hip_runtime.h>
#include <cstddef>
#include <cstdint>

// Problem constants (fixed by the reference)
constexpr int N_ = 100000;   // nodes
constexpr int E_ = 1600000;  // edges
constexpr int G_ = 128;      // graphs
#define SLOPE 0.15f

__device__ __forceinline__ float leaky(float v) { return v > 0.0f ? v : SLOPE * v; }

// ===========================================================================
// CSR construction: histogram -> 2-level exclusive scan -> scatter
// ===========================================================================
__global__ __launch_bounds__(256) void hist_kernel(const int* __restrict__ ei,
                                                   int* __restrict__ h)
{
    int t = blockIdx.x * 256 + threadIdx.x;
    if (t < E_) atomicAdd(&h[ei[E_ + t]], 1);   // edge_index row 1 = target
}

__global__ __launch_bounds__(256) void scan1_kernel(const int* __restrict__ h,
                                                    int* __restrict__ bsums)
{
    __shared__ int s[256];
    int i = blockIdx.x * 256 + threadIdx.x;
    int v = (i < N_) ? h[i] : 0;
    s[threadIdx.x] = v;
    __syncthreads();
    for (int o = 128; o > 0; o >>= 1) {
        if (threadIdx.x < o) s[threadIdx.x] += s[threadIdx.x + o];
        __syncthreads();
    }
    if (threadIdx.x == 0) bsums[blockIdx.x] = s[0];
}

__global__ __launch_bounds__(512) void scan2_kernel(int* __restrict__ bsums, int nb)
{
    __shared__ int s[512];
    int t = threadIdx.x;
    int v = (t < nb) ? bsums[t] : 0;
    s[t] = v;
    __syncthreads();
    for (int o = 1; o < 512; o <<= 1) {
        int add = (t >= o) ? s[t - o] : 0;
        __syncthreads();
        s[t] += add;
        __syncthreads();
    }
    bsums[t] = s[t] - v;   // exclusive
}

__global__ __launch_bounds__(256) void scan3_kernel(const int* __restrict__ h,
                                                    const int* __restrict__ bsums,
                                                    int* __restrict__ rowptr,
                                                    int* __restrict__ cursor)
{
    __shared__ int s[256];
    int i = blockIdx.x * 256 + threadIdx.x;
    int v = (i < N_) ? h[i] : 0;
    s[threadIdx.x] = v;
    __syncthreads();
    for (int o = 1; o < 256; o <<= 1) {
        int add = (threadIdx.x >= o) ? s[threadIdx.x - o] : 0;
        __syncthreads();
        s[threadIdx.x] += add;
        __syncthreads();
    }
    if (i < N_) {
        int incl = s[threadIdx.x] + bsums[blockIdx.x];
        int excl = incl - v;
        rowptr[i] = excl;
        cursor[i] = excl;
        if (i == N_ - 1) rowptr[N_] = incl;   // == E_
    }
}

__global__ __launch_bounds__(256) void scatter_kernel(const int* __restrict__ ei,
                                                      int* __restrict__ cursor,
                                                      int* __restrict__ eids)
{
    int e = blockIdx.x * 256 + threadIdx.x;
    if (e < E_) {
        int t = ei[E_ + e];
        int pos = atomicAdd(&cursor[t], 1);
        eids[pos] = e;
    }
}

// ===========================================================================
// Edge MLPs (both convs, they depend only on edge_attr), processed in CSR
// order, 2 edges/thread, plain coalesced stores (NO atomics).
// ===========================================================================
__device__ __forceinline__ void conv_pair_store(
    const float* __restrict__ sWbase,
    const float* __restrict__ ea0, const float* __restrict__ ea1,
    float* __restrict__ o0, float* __restrict__ o1, bool v0, bool v1)
{
    const float* w1 = sWbase;
    const float* b1 = sWbase + 2048;
    const float* w2 = sWbase + 2112;
    const float* b2 = sWbase + 6208;

    float ta[64], tb[64];
#pragma unroll
    for (int j = 0; j < 64; j += 4) {
        float a0 = b1[j], a1 = b1[j + 1], a2 = b1[j + 2], a3 = b1[j + 3];
        float c0 = a0, c1 = a1, c2 = a2, c3 = a3;
#pragma unroll
        for (int k = 0; k < 32; k++) {
            float4 w = *reinterpret_cast<const float4*>(&w1[k * 64 + j]);
            float e0 = ea0[k], e1 = ea1[k];
            a0 += e0 * w.x; a1 += e0 * w.y; a2 += e0 * w.z; a3 += e0 * w.w;
            c0 += e1 * w.x; c1 += e1 * w.y; c2 += e1 * w.z; c3 += e1 * w.w;
        }
        ta[j] = leaky(a0); ta[j + 1] = leaky(a1); ta[j + 2] = leaky(a2); ta[j + 3] = leaky(a3);
        tb[j] = leaky(c0); tb[j + 1] = leaky(c1); tb[j + 2] = leaky(c2); tb[j + 3] = leaky(c3);
    }
#pragma unroll
    for (int j = 0; j < 64; j += 4) {
        float a0 = b2[j], a1 = b2[j + 1], a2 = b2[j + 2], a3 = b2[j + 3];
        float c0 = a0, c1 = a1, c2 = a2, c3 = a3;
#pragma unroll
        for (int k = 0; k < 64; k++) {
            float4 w = *reinterpret_cast<const float4*>(&w2[k * 64 + j]);
            float t0 = ta[k], t1 = tb[k];
            a0 += t0 * w.x; a1 += t0 * w.y; a2 += t0 * w.z; a3 += t0 * w.w;
            c0 += t1 * w.x; c1 += t1 * w.y; c2 += t1 * w.z; c3 += t1 * w.w;
        }
        if (v0) { float4 o; o.x = a0; o.y = a1; o.z = a2; o.w = a3;
                  *reinterpret_cast<float4*>(&o0[j]) = o; }
        if (v1) { float4 o; o.x = c0; o.y = c1; o.z = c2; o.w = c3;
                  *reinterpret_cast<float4*>(&o1[j]) = o; }
    }
}

__global__ __launch_bounds__(256) void mlp_chunk_kernel(
    const float* __restrict__ edge_attr, const int* __restrict__ eids,
    const int* __restrict__ rowptr,
    const float* __restrict__ e1w1, const float* __restrict__ e1b1,
    const float* __restrict__ e1w2, const float* __restrict__ e1b2,
    const float* __restrict__ e2w1, const float* __restrict__ e2b1,
    const float* __restrict__ e2w2, const float* __restrict__ e2b2,
    float* __restrict__ emb1, float* __restrict__ emb2,
    int cs, int ce, int cap)
{
    __shared__ __align__(16) float sW[2 * 6272];
    for (int t = threadIdx.x; t < 2048; t += 256) sW[t]         = e1w1[t];
    for (int t = threadIdx.x; t < 64;   t += 256) sW[2048 + t]  = e1b1[t];
    for (int t = threadIdx.x; t < 4096; t += 256) sW[2112 + t]  = e1w2[t];
    for (int t = threadIdx.x; t < 64;   t += 256) sW[6208 + t]  = e1b2[t];
    for (int t = threadIdx.x; t < 2048; t += 256) sW[6272 + t]  = e2w1[t];
    for (int t = threadIdx.x; t < 64;   t += 256) sW[8320 + t]  = e2b1[t];
    for (int t = threadIdx.x; t < 4096; t += 256) sW[8384 + t]  = e2w2[t];
    for (int t = threadIdx.x; t < 64;   t += 256) sW[12480 + t] = e2b2[t];
    __syncthreads();

    int base = rowptr[cs];
    int end  = rowptr[ce];
    int idx0 = blockIdx.x * 512 + threadIdx.x;
    int idx1 = idx0 + 256;
    bool v0 = (base + idx0 < end) && (idx0 < cap);
    bool v1 = (base + idx1 < end) && (idx1 < cap);
    if (!v0 && !v1) return;

    int e0 = v0 ? eids[base + idx0] : 0;
    int e1 = v1 ? eids[base + idx1] : 0;

    float ea0[32], ea1[32];
    {
        const float4* p0 = reinterpret_cast<const float4*>(edge_attr + (size_t)e0 * 32);
        const float4* p1 = reinterpret_cast<const float4*>(edge_attr + (size_t)e1 * 32);
#pragma unroll
        for (int r = 0; r < 8; r++) {
            float4 v = p0[r];
            ea0[4 * r] = v.x; ea0[4 * r + 1] = v.y; ea0[4 * r + 2] = v.z; ea0[4 * r + 3] = v.w;
            float4 u = p1[r];
            ea1[4 * r] = u.x; ea1[4 * r + 1] = u.y; ea1[4 * r + 2] = u.z; ea1[4 * r + 3] = u.w;
        }
    }

    float* o10 = emb1 + (size_t)idx0 * 64;
    float* o11 = emb1 + (size_t)idx1 * 64;
    float* o20 = emb2 + (size_t)idx0 * 64;
    float* o21 = emb2 + (size_t)idx1 * 64;
    conv_pair_store(&sW[0],    ea0, ea1, o10, o11, v0, v1);
    conv_pair_store(&sW[6272], ea0, ea1, o20, o21, v0, v1);
}

// ===========================================================================
// Gather: one wave per node, lane = feature; contiguous coalesced reads.
// ===========================================================================
__global__ __launch_bounds__(256) void gather_kernel(
    const int* __restrict__ rowptr,
    const float* __restrict__ emb1, const float* __restrict__ emb2,
    float* __restrict__ agg1, float* __restrict__ agg2, int cs, int ce)
{
    int wid = threadIdx.x >> 6, lane = threadIdx.x & 63;
    int node = cs + blockIdx.x * 4 + wid;
    if (node >= ce) return;
    int base = rowptr[cs];
    int s = rowptr[node], t = rowptr[node + 1];
    float a1 = 0.f, a2 = 0.f;
    const float* p1 = emb1 + (size_t)(s - base) * 64 + lane;
    const float* p2 = emb2 + (size_t)(s - base) * 64 + lane;
    for (int p = s; p < t; ++p) {
        a1 += *p1; a2 += *p2;
        p1 += 64;  p2 += 64;
    }
    agg1[(size_t)node * 64 + lane] = a1;
    agg2[(size_t)node * 64 + lane] = a2;
}

// ===========================================================================
// Fallback (small ws): atomic edge kernel (proven correct in round 2)
// ===========================================================================
__device__ __forceinline__ void conv_pair_atomic(
    const float* __restrict__ sWbase,
    const float* __restrict__ ea0, const float* __restrict__ ea1,
    float* __restrict__ aggp0, float* __restrict__ aggp1)
{
    const float* w1 = sWbase;
    const float* b1 = sWbase + 2048;
    const float* w2 = sWbase + 2112;
    const float* b2 = sWbase + 6208;
    float ta[64], tb[64];
#pragma unroll
    for (int j = 0; j < 64; j += 4) {
        float a0 = b1[j], a1 = b1[j + 1], a2 = b1[j + 2], a3 = b1[j + 3];
        float c0 = a0, c1 = a1, c2 = a2, c3 = a3;
#pragma unroll
        for (int k = 0; k < 32; k++) {
            float4 w = *reinterpret_cast<const float4*>(&w1[k * 64 + j]);
            float e0 = ea0[k], e1 = ea1[k];
            a0 += e0 * w.x; a1 += e0 * w.y; a2 += e0 * w.z; a3 += e0 * w.w;
            c0 += e1 * w.x; c1 += e1 * w.y; c2 += e1 * w.z; c3 += e1 * w.w;
        }
        ta[j] = leaky(a0); ta[j + 1] = leaky(a1); ta[j + 2] = leaky(a2); ta[j + 3] = leaky(a3);
        tb[j] = leaky(c0); tb[j + 1] = leaky(c1); tb[j + 2] = leaky(c2); tb[j + 3] = leaky(c3);
    }
#pragma unroll
    for (int j = 0; j < 64; j += 4) {
        float a0 = b2[j], a1 = b2[j + 1], a2 = b2[j + 2], a3 = b2[j + 3];
        float c0 = a0, c1 = a1, c2 = a2, c3 = a3;
#pragma unroll
        for (int k = 0; k < 64; k++) {
            float4 w = *reinterpret_cast<const float4*>(&w2[k * 64 + j]);
            float t0 = ta[k], t1 = tb[k];
            a0 += t0 * w.x; a1 += t0 * w.y; a2 += t0 * w.z; a3 += t0 * w.w;
            c0 += t1 * w.x; c1 += t1 * w.y; c2 += t1 * w.z; c3 += t1 * w.w;
        }
        atomicAdd(&aggp0[j], a0); atomicAdd(&aggp0[j + 1], a1);
        atomicAdd(&aggp0[j + 2], a2); atomicAdd(&aggp0[j + 3], a3);
        atomicAdd(&aggp1[j], c0); atomicAdd(&aggp1[j + 1], c1);
        atomicAdd(&aggp1[j + 2], c2); atomicAdd(&aggp1[j + 3], c3);
    }
}

__global__ __launch_bounds__(256) void edge_kernel_atomic(
    const float* __restrict__ edge_attr, const int* __restrict__ ei,
    const float* __restrict__ e1w1, const float* __restrict__ e1b1,
    const float* __restrict__ e1w2, const float* __restrict__ e1b2,
    const float* __restrict__ e2w1, const float* __restrict__ e2b1,
    const float* __restrict__ e2w2, const float* __restrict__ e2b2,
    float* __restrict__ agg1, float* __restrict__ agg2)
{
    __shared__ __align__(16) float sW[2 * 6272];
    for (int t = threadIdx.x; t < 2048; t += 256) sW[t]         = e1w1[t];
    for (int t = threadIdx.x; t < 64;   t += 256) sW[2048 + t]  = e1b1[t];
    for (int t = threadIdx.x; t < 4096; t += 256) sW[2112 + t]  = e1w2[t];
    for (int t = threadIdx.x; t < 64;   t += 256) sW[6208 + t]  = e1b2[t];
    for (int t = threadIdx.x; t < 2048; t += 256) sW[6272 + t]  = e2w1[t];
    for (int t = threadIdx.x; t < 64;   t += 256) sW[8320 + t]  = e2b1[t];
    for (int t = threadIdx.x; t < 4096; t += 256) sW[8384 + t]  = e2w2[t];
    for (int t = threadIdx.x; t < 64;   t += 256) sW[12480 + t] = e2b2[t];
    __syncthreads();

    int e0 = blockIdx.x * 512 + threadIdx.x;
    int e1 = e0 + 256;
    int tg0 = ei[E_ + e0];
    int tg1 = ei[E_ + e1];

    float ea0[32], ea1[32];
    {
        const float4* p0 = reinterpret_cast<const float4*>(edge_attr + (size_t)e0 * 32);
        const float4* p1 = reinterpret_cast<const float4*>(edge_attr + (size_t)e1 * 32);
#pragma unroll
        for (int r = 0; r < 8; r++) {
            float4 v = p0[r];
            ea0[4 * r] = v.x; ea0[4 * r + 1] = v.y; ea0[4 * r + 2] = v.z; ea0[4 * r + 3] = v.w;
            float4 u = p1[r];
            ea1[4 * r] = u.x; ea1[4 * r + 1] = u.y; ea1[4 * r + 2] = u.z; ea1[4 * r + 3] = u.w;
        }
    }
    conv_pair_atomic(&sW[0],    ea0, ea1, agg1 + (size_t)tg0 * 64, agg1 + (size_t)tg1 * 64);
    conv_pair_atomic(&sW[6272], ea0, ea1, agg2 + (size_t)tg0 * 64, agg2 + (size_t)tg1 * 64);
}

// ===========================================================================
// Node update conv1 (in place over agg1); deg derived from rowptr.
// ===========================================================================
__global__ __launch_bounds__(256) void node1_kernel(
    const float* __restrict__ x, float* __restrict__ agg1,
    const int* __restrict__ rowptr,
    const float* __restrict__ n1w, const float* __restrict__ n1b)
{
    __shared__ __align__(16) float sA[4096], sB[4096], sb[64];
    for (int t = threadIdx.x; t < 4096; t += 256) { sA[t] = n1w[t]; sB[t] = n1w[4096 + t]; }
    if (threadIdx.x < 64) sb[threadIdx.x] = n1b[threadIdx.x];
    __syncthreads();

    int i = blockIdx.x * 256 + threadIdx.x;
    if (i >= N_) return;

    float xi[64], ag[64];
    {
        const float4* px = reinterpret_cast<const float4*>(x + (size_t)i * 64);
        const float4* pa = reinterpret_cast<const float4*>(agg1 + (size_t)i * 64);
#pragma unroll
        for (int r = 0; r < 16; r++) {
            float4 v = px[r];
            xi[4 * r] = v.x; xi[4 * r + 1] = v.y; xi[4 * r + 2] = v.z; xi[4 * r + 3] = v.w;
            float4 a = pa[r];
            ag[4 * r] = a.x; ag[4 * r + 1] = a.y; ag[4 * r + 2] = a.z; ag[4 * r + 3] = a.w;
        }
    }
    float d = (float)(rowptr[i + 1] - rowptr[i]);

#pragma unroll
    for (int j = 0; j < 64; j += 4) {
        float sx = sb[j], sy = sb[j + 1], sz = sb[j + 2], sw_ = sb[j + 3];
        float gx = 0.f, gy = 0.f, gz = 0.f, gw = 0.f;
#pragma unroll
        for (int k = 0; k < 64; k++) {
            float4 wa = *reinterpret_cast<const float4*>(&sA[k * 64 + j]);
            float xv = xi[k];
            sx += xv * wa.x; sy += xv * wa.y; sz += xv * wa.z; sw_ += xv * wa.w;
            float4 wb = *reinterpret_cast<const float4*>(&sB[k * 64 + j]);
            float av = ag[k];
            gx += av * wb.x; gy += av * wb.y; gz += av * wb.z; gw += av * wb.w;
        }
        float4 o;
        o.x = leaky(d * sx + gx);
        o.y = leaky(d * sy + gy);
        o.z = leaky(d * sz + gz);
        o.w = leaky(d * sw_ + gw);
        *reinterpret_cast<float4*>(&agg1[(size_t)i * 64 + j]) = o;
    }
}

// ===========================================================================
// Node update conv2 + heads (z/mu/logvar). No pooling atomics here.
// ===========================================================================
__global__ __launch_bounds__(256) void node2_kernel(
    const float* __restrict__ h1, const float* __restrict__ agg2,
    const int* __restrict__ rowptr,
    const float* __restrict__ n2w, const float* __restrict__ n2b,
    const float* __restrict__ mu_w, const float* __restrict__ mu_b,
    const float* __restrict__ lv_w, const float* __restrict__ lv_b,
    float* __restrict__ out)
{
    __shared__ __align__(16) float sA[4096], sB[4096], sb[64];
    __shared__ __align__(16) float sMu[2048], sLv[2048], sMb[32], sLb[32];
    for (int t = threadIdx.x; t < 4096; t += 256) { sA[t] = n2w[t]; sB[t] = n2w[4096 + t]; }
    for (int t = threadIdx.x; t < 2048; t += 256) { sMu[t] = mu_w[t]; sLv[t] = lv_w[t]; }
    if (threadIdx.x < 64) sb[threadIdx.x] = n2b[threadIdx.x];
    if (threadIdx.x < 32) { sMb[threadIdx.x] = mu_b[threadIdx.x]; sLb[threadIdx.x] = lv_b[threadIdx.x]; }
    __syncthreads();

    int i = blockIdx.x * 256 + threadIdx.x;
    if (i >= N_) return;

    float hi[64], ag[64];
    {
        const float4* ph = reinterpret_cast<const float4*>(h1 + (size_t)i * 64);
        const float4* pa = reinterpret_cast<const float4*>(agg2 + (size_t)i * 64);
#pragma unroll
        for (int r = 0; r < 16; r++) {
            float4 v = ph[r];
            hi[4 * r] = v.x; hi[4 * r + 1] = v.y; hi[4 * r + 2] = v.z; hi[4 * r + 3] = v.w;
            float4 a = pa[r];
            ag[4 * r] = a.x; ag[4 * r + 1] = a.y; ag[4 * r + 2] = a.z; ag[4 * r + 3] = a.w;
        }
    }
    float d = (float)(rowptr[i + 1] - rowptr[i]);

    float t2[64];
#pragma unroll
    for (int j = 0; j < 64; j += 4) {
        float sx = sb[j], sy = sb[j + 1], sz = sb[j + 2], sw_ = sb[j + 3];
        float gx = 0.f, gy = 0.f, gz = 0.f, gw = 0.f;
#pragma unroll
        for (int k = 0; k < 64; k++) {
            float4 wa = *reinterpret_cast<const float4*>(&sA[k * 64 + j]);
            float hv = hi[k];
            sx += hv * wa.x; sy += hv * wa.y; sz += hv * wa.z; sw_ += hv * wa.w;
            float4 wb = *reinterpret_cast<const float4*>(&sB[k * 64 + j]);
            float av = ag[k];
            gx += av * wb.x; gy += av * wb.y; gz += av * wb.z; gw += av * wb.w;
        }
        t2[j]     = leaky(d * sx + gx);
        t2[j + 1] = leaky(d * sy + gy);
        t2[j + 2] = leaky(d * sz + gz);
        t2[j + 3] = leaky(d * sw_ + gw);
    }

#pragma unroll
    for (int j = 0; j < 32; j += 4) {
        float ax = sMb[j], ay = sMb[j + 1], az = sMb[j + 2], aw = sMb[j + 3];
#pragma unroll
        for (int k = 0; k < 64; k++) {
            float4 w = *reinterpret_cast<const float4*>(&sMu[k * 32 + j]);
            float t = t2[k];
            ax += t * w.x; ay += t * w.y; az += t * w.z; aw += t * w.w;
        }
        float4 o; o.x = ax; o.y = ay; o.z = az; o.w = aw;
        *reinterpret_cast<float4*>(&out[(size_t)i * 32 + j]) = o;                    // z
        *reinterpret_cast<float4*>(&out[(size_t)N_ * 32 + (size_t)i * 32 + j]) = o;  // mu
    }
#pragma unroll
    for (int j = 0; j < 32; j += 4) {
        float ax = sLb[j], ay = sLb[j + 1], az = sLb[j + 2], aw = sLb[j + 3];
#pragma unroll
        for (int k = 0; k < 64; k++) {
            float4 w = *reinterpret_cast<const float4*>(&sLv[k * 32 + j]);
            float t = t2[k];
            ax += t * w.x; ay += t * w.y; az += t * w.z; aw += t * w.w;
        }
        float4 o; o.x = ax; o.y = ay; o.z = az; o.w = aw;
        *reinterpret_cast<float4*>(&out[2ull * N_ * 32 + (size_t)i * 32 + j]) = o;   // logvar
    }
}

// ===========================================================================
// Pool: block per graph; batch is sorted -> binary search range; block reduce.
// ===========================================================================
__global__ __launch_bounds__(256) void pool_kernel(
    const float* __restrict__ z, const int* __restrict__ batch,
    const float* __restrict__ cls_w, const float* __restrict__ cls_b,
    float* __restrict__ out)
{
    __shared__ int sLo, sHi;
    __shared__ float sred[256];
    __shared__ float pooled[32];
    int g = blockIdx.x;
    if (threadIdx.x == 0) {
        int lo = 0, hi = N_;
        while (lo < hi) { int m = (lo + hi) >> 1; if (batch[m] < g) lo = m + 1; else hi = m; }
        sLo = lo;
        int lo2 = lo; hi = N_;
        while (lo2 < hi) { int m = (lo2 + hi) >> 1; if (batch[m] < g + 1) lo2 = m + 1; else hi = m; }
        sHi = lo2;
    }
    __syncthreads();
    int lo = sLo, hi = sHi;
    int f = threadIdx.x & 31, r = threadIdx.x >> 5;
    float acc = 0.f;
    for (int i = lo + r; i < hi; i += 8) acc += z[(size_t)i * 32 + f];
    sred[threadIdx.x] = acc;
    __syncthreads();
    if (threadIdx.x < 128) sred[threadIdx.x] += sred[threadIdx.x + 128];
    __syncthreads();
    if (threadIdx.x < 64)  sred[threadIdx.x] += sred[threadIdx.x + 64];
    __syncthreads();
    if (threadIdx.x < 32) {
        float s = sred[threadIdx.x] + sred[threadIdx.x + 32];
        pooled[threadIdx.x] = s / fmaxf((float)(hi - lo), 1.0f);
    }
    __syncthreads();
    if (threadIdx.x < 10) {
        int j = threadIdx.x;
        float accj = cls_b[j];
#pragma unroll
        for (int k = 0; k < 32; k++) accj += pooled[k] * cls_w[k * 10 + j];
        out[3ull * N_ * 32 + (size_t)g * 10 + j] = accj;
    }
}

// ===========================================================================
extern "C" void kernel_launch(void* const* d_in, const int* in_sizes, int n_in,
                              void* d_out, int out_size, void* d_ws, size_t ws_size,
                              hipStream_t stream)
{
    const float* x         = (const float*)d_in[0];
    const int*   ei        = (const int*)  d_in[1];
    const float* edge_attr = (const float*)d_in[2];
    const int*   batch     = (const int*)  d_in[3];
    const float* e1w1 = (const float*)d_in[4];
    const float* e1b1 = (const float*)d_in[5];
    const float* e1w2 = (const float*)d_in[6];
    const float* e1b2 = (const float*)d_in[7];
    const float* n1w  = (const float*)d_in[8];
    const float* n1b  = (const float*)d_in[9];
    const float* e2w1 = (const float*)d_in[10];
    const float* e2b1 = (const float*)d_in[11];
    const float* e2w2 = (const float*)d_in[12];
    const float* e2b2 = (const float*)d_in[13];
    const float* n2w  = (const float*)d_in[14];
    const float* n2b  = (const float*)d_in[15];
    const float* mu_w = (const float*)d_in[16];
    const float* mu_b = (const float*)d_in[17];
    const float* lv_w = (const float*)d_in[18];
    const float* lv_b = (const float*)d_in[19];
    const float* cls_w = (const float*)d_in[20];
    const float* cls_b = (const float*)d_in[21];

    float* out = (float*)d_out;
    char*  wsb = (char*)d_ws;

    // ws layout (all 256B-aligned)
    size_t off = 0;
    auto alloc = [&](size_t bytes) { size_t o = off; off = (off + bytes + 255) & ~(size_t)255; return o; };
    int*   rowptr = (int*)  (wsb + alloc((N_ + 1) * sizeof(int)));
    int*   h      = (int*)  (wsb + alloc(N_ * sizeof(int)));
    int*   cursor = (int*)  (wsb + alloc(N_ * sizeof(int)));
    int*   eids   = (int*)  (wsb + alloc((size_t)E_ * sizeof(int)));
    int*   bsums  = (int*)  (wsb + alloc(512 * sizeof(int)));
    float* agg1   = (float*)(wsb + alloc((size_t)N_ * 64 * sizeof(float)));
    float* agg2   = (float*)(wsb + alloc((size_t)N_ * 64 * sizeof(float)));
    size_t fixed_end = off;

    // choose chunk count C from ws_size (deterministic -> graph-capture safe)
    int C = 0; size_t cap = 0;
    const int cands[6] = {1, 2, 4, 8, 16, 32};
    for (int ci = 0; ci < 6; ci++) {
        int c = cands[ci];
        size_t cp = (c == 1) ? (size_t)E_ : ((size_t)E_ / c + (size_t)E_ / (4 * c) + 2048);
        if (fixed_end + 2 * (cp * 64 * sizeof(float) + 256) <= ws_size) { C = c; cap = cp; break; }
    }
    float* emb1 = nullptr; float* emb2 = nullptr;
    if (C) {
        emb1 = (float*)(wsb + alloc(cap * 64 * sizeof(float)));
        emb2 = (float*)(wsb + alloc(cap * 64 * sizeof(float)));
    }

    const int nb = (N_ + 255) / 256;   // 391

    // CSR build (always: rowptr also provides deg for node kernels)
    hipMemsetAsync(h, 0, (size_t)N_ * sizeof(int), stream);
    hist_kernel<<<(E_ + 255) / 256, 256, 0, stream>>>(ei, h);
    scan1_kernel<<<nb, 256, 0, stream>>>(h, bsums);
    scan2_kernel<<<1, 512, 0, stream>>>(bsums, nb);
    scan3_kernel<<<nb, 256, 0, stream>>>(h, bsums, rowptr, cursor);

    if (C) {
        scatter_kernel<<<(E_ + 255) / 256, 256, 0, stream>>>(ei, cursor, eids);
        int NC = (N_ + C - 1) / C;
        for (int c = 0; c < C; c++) {
            int cs = c * NC;
            int ce = (cs + NC < N_) ? cs + NC : N_;
            mlp_chunk_kernel<<<(int)((cap + 511) / 512), 256, 0, stream>>>(
                edge_attr, eids, rowptr,
                e1w1, e1b1, e1w2, e1b2, e2w1, e2b1, e2w2, e2b2,
                emb1, emb2, cs, ce, (int)cap);
            gather_kernel<<<(NC + 3) / 4, 256, 0, stream>>>(
                rowptr, emb1, emb2, agg1, agg2, cs, ce);
        }
    } else {
        hipMemsetAsync(agg1, 0, 2ull * N_ * 64 * sizeof(float), stream);
        edge_kernel_atomic<<<E_ / 512, 256, 0, stream>>>(
            edge_attr, ei, e1w1, e1b1, e1w2, e1b2, e2w1, e2b1, e2w2, e2b2, agg1, agg2);
    }

    node1_kernel<<<nb, 256, 0, stream>>>(x, agg1, rowptr, n1w, n1b);
    node2_kernel<<<nb, 256, 0, stream>>>(agg1, agg2, rowptr, n2w, n2b,
                                         mu_w, mu_b, lv_w, lv_b, out);
    pool_kernel<<<G_, 256, 0, stream>>>(out, batch, cls_w, cls_b, out);
}

// Round 15
// 2217.086 us; speedup vs baseline: 7.7931x; 7.7931x over previous
//
#include <hip/hip_runtime.h>
#include <cstddef>
#include <cstdint>

// Problem constants (fixed by the reference)
constexpr int N_ = 100000;   // nodes
constexpr int E_ = 1600000;  // edges
constexpr int G_ = 128;      // graphs
#define SLOPE 0.15f

__device__ __forceinline__ float leaky(float v) { return v > 0.0f ? v : SLOPE * v; }

// ===========================================================================
// CSR construction: histogram -> 2-level exclusive scan -> scatter
// ===========================================================================
__global__ __launch_bounds__(256) void hist_kernel(const int* __restrict__ ei,
                                                   int* __restrict__ h)
{
    int t = blockIdx.x * 256 + threadIdx.x;
    if (t < E_) atomicAdd(&h[ei[E_ + t]], 1);   // edge_index row 1 = target
}

__global__ __launch_bounds__(256) void scan1_kernel(const int* __restrict__ h,
                                                    int* __restrict__ bsums)
{
    __shared__ int s[256];
    int i = blockIdx.x * 256 + threadIdx.x;
    int v = (i < N_) ? h[i] : 0;
    s[threadIdx.x] = v;
    __syncthreads();
    for (int o = 128; o > 0; o >>= 1) {
        if (threadIdx.x < o) s[threadIdx.x] += s[threadIdx.x + o];
        __syncthreads();
    }
    if (threadIdx.x == 0) bsums[blockIdx.x] = s[0];
}

__global__ __launch_bounds__(512) void scan2_kernel(int* __restrict__ bsums, int nb)
{
    __shared__ int s[512];
    int t = threadIdx.x;
    int v = (t < nb) ? bsums[t] : 0;
    s[t] = v;
    __syncthreads();
    for (int o = 1; o < 512; o <<= 1) {
        int add = (t >= o) ? s[t - o] : 0;
        __syncthreads();
        s[t] += add;
        __syncthreads();
    }
    bsums[t] = s[t] - v;   // exclusive
}

__global__ __launch_bounds__(256) void scan3_kernel(const int* __restrict__ h,
                                                    const int* __restrict__ bsums,
                                                    int* __restrict__ rowptr,
                                                    int* __restrict__ cursor)
{
    __shared__ int s[256];
    int i = blockIdx.x * 256 + threadIdx.x;
    int v = (i < N_) ? h[i] : 0;
    s[threadIdx.x] = v;
    __syncthreads();
    for (int o = 1; o < 256; o <<= 1) {
        int add = (threadIdx.x >= o) ? s[threadIdx.x - o] : 0;
        __syncthreads();
        s[threadIdx.x] += add;
        __syncthreads();
    }
    if (i < N_) {
        int incl = s[threadIdx.x] + bsums[blockIdx.x];
        int excl = incl - v;
        rowptr[i] = excl;
        cursor[i] = excl;
        if (i == N_ - 1) rowptr[N_] = incl;   // == E_
    }
}

__global__ __launch_bounds__(256) void scatter_kernel(const int* __restrict__ ei,
                                                      int* __restrict__ cursor,
                                                      int* __restrict__ eids)
{
    int e = blockIdx.x * 256 + threadIdx.x;
    if (e < E_) {
        int t = ei[E_ + e];
        int pos = atomicAdd(&cursor[t], 1);
        eids[pos] = e;
    }
}

// ===========================================================================
// Edge MLP for ONE conv, ONE edge per thread (round-6 lesson: 2 edges/thread
// needs ~200 live floats -> VGPR cap 256 -> scratch spill -> 20 GB HBM
// traffic. 1 edge/thread = ~105 live floats, no spill.)
// ===========================================================================
__device__ __forceinline__ void conv_store_1(
    const float* __restrict__ sWbase,   // LDS: w1[32][64], b1[64], w2[64][64], b2[64]
    const float* __restrict__ ea,
    float* __restrict__ o)
{
    const float* w1 = sWbase;
    const float* b1 = sWbase + 2048;
    const float* w2 = sWbase + 2112;
    const float* b2 = sWbase + 6208;

    float t1[64];
#pragma unroll
    for (int j = 0; j < 64; j += 4) {
        float a0 = b1[j], a1 = b1[j + 1], a2 = b1[j + 2], a3 = b1[j + 3];
#pragma unroll
        for (int k = 0; k < 32; k++) {
            float4 w = *reinterpret_cast<const float4*>(&w1[k * 64 + j]);
            float e0 = ea[k];
            a0 += e0 * w.x; a1 += e0 * w.y; a2 += e0 * w.z; a3 += e0 * w.w;
        }
        t1[j] = leaky(a0); t1[j + 1] = leaky(a1); t1[j + 2] = leaky(a2); t1[j + 3] = leaky(a3);
    }
#pragma unroll
    for (int j = 0; j < 64; j += 4) {
        float a0 = b2[j], a1 = b2[j + 1], a2 = b2[j + 2], a3 = b2[j + 3];
#pragma unroll
        for (int k = 0; k < 64; k++) {
            float4 w = *reinterpret_cast<const float4*>(&w2[k * 64 + j]);
            float t0 = t1[k];
            a0 += t0 * w.x; a1 += t0 * w.y; a2 += t0 * w.z; a3 += t0 * w.w;
        }
        float4 ov; ov.x = a0; ov.y = a1; ov.z = a2; ov.w = a3;
        *reinterpret_cast<float4*>(&o[j]) = ov;
    }
}

__global__ __launch_bounds__(256) void mlp_chunk_kernel(
    const float* __restrict__ edge_attr, const int* __restrict__ eids,
    const int* __restrict__ rowptr,
    const float* __restrict__ e1w1, const float* __restrict__ e1b1,
    const float* __restrict__ e1w2, const float* __restrict__ e1b2,
    const float* __restrict__ e2w1, const float* __restrict__ e2b1,
    const float* __restrict__ e2w2, const float* __restrict__ e2b2,
    float* __restrict__ emb1, float* __restrict__ emb2,
    int cs, int ce, int cap)
{
    __shared__ __align__(16) float sW[2 * 6272];
    for (int t = threadIdx.x; t < 2048; t += 256) sW[t]         = e1w1[t];
    for (int t = threadIdx.x; t < 64;   t += 256) sW[2048 + t]  = e1b1[t];
    for (int t = threadIdx.x; t < 4096; t += 256) sW[2112 + t]  = e1w2[t];
    for (int t = threadIdx.x; t < 64;   t += 256) sW[6208 + t]  = e1b2[t];
    for (int t = threadIdx.x; t < 2048; t += 256) sW[6272 + t]  = e2w1[t];
    for (int t = threadIdx.x; t < 64;   t += 256) sW[8320 + t]  = e2b1[t];
    for (int t = threadIdx.x; t < 4096; t += 256) sW[8384 + t]  = e2w2[t];
    for (int t = threadIdx.x; t < 64;   t += 256) sW[12480 + t] = e2b2[t];
    __syncthreads();

    int base = rowptr[cs];
    int end  = rowptr[ce];
    int idx = blockIdx.x * 256 + threadIdx.x;
    if (base + idx >= end || idx >= cap) return;

    int e = eids[base + idx];

    float ea[32];
    {
        const float4* p = reinterpret_cast<const float4*>(edge_attr + (size_t)e * 32);
#pragma unroll
        for (int r = 0; r < 8; r++) {
            float4 v = p[r];
            ea[4 * r] = v.x; ea[4 * r + 1] = v.y; ea[4 * r + 2] = v.z; ea[4 * r + 3] = v.w;
        }
    }

    conv_store_1(&sW[0],    ea, emb1 + (size_t)idx * 64);
    conv_store_1(&sW[6272], ea, emb2 + (size_t)idx * 64);
}

// ===========================================================================
// Gather: one wave per node, lane = feature; contiguous coalesced reads.
// ===========================================================================
__global__ __launch_bounds__(256) void gather_kernel(
    const int* __restrict__ rowptr,
    const float* __restrict__ emb1, const float* __restrict__ emb2,
    float* __restrict__ agg1, float* __restrict__ agg2, int cs, int ce)
{
    int wid = threadIdx.x >> 6, lane = threadIdx.x & 63;
    int node = cs + blockIdx.x * 4 + wid;
    if (node >= ce) return;
    int base = rowptr[cs];
    int s = rowptr[node], t = rowptr[node + 1];
    float a1 = 0.f, a2 = 0.f;
    const float* p1 = emb1 + (size_t)(s - base) * 64 + lane;
    const float* p2 = emb2 + (size_t)(s - base) * 64 + lane;
    for (int p = s; p < t; ++p) {
        a1 += *p1; a2 += *p2;
        p1 += 64;  p2 += 64;
    }
    agg1[(size_t)node * 64 + lane] = a1;
    agg2[(size_t)node * 64 + lane] = a2;
}

// ===========================================================================
// Fallback (small ws): atomic edge kernel, 1 edge/thread (no-spill variant)
// ===========================================================================
__device__ __forceinline__ void conv_atomic_1(
    const float* __restrict__ sWbase,
    const float* __restrict__ ea,
    float* __restrict__ aggp)
{
    const float* w1 = sWbase;
    const float* b1 = sWbase + 2048;
    const float* w2 = sWbase + 2112;
    const float* b2 = sWbase + 6208;

    float t1[64];
#pragma unroll
    for (int j = 0; j < 64; j += 4) {
        float a0 = b1[j], a1 = b1[j + 1], a2 = b1[j + 2], a3 = b1[j + 3];
#pragma unroll
        for (int k = 0; k < 32; k++) {
            float4 w = *reinterpret_cast<const float4*>(&w1[k * 64 + j]);
            float e0 = ea[k];
            a0 += e0 * w.x; a1 += e0 * w.y; a2 += e0 * w.z; a3 += e0 * w.w;
        }
        t1[j] = leaky(a0); t1[j + 1] = leaky(a1); t1[j + 2] = leaky(a2); t1[j + 3] = leaky(a3);
    }
#pragma unroll
    for (int j = 0; j < 64; j += 4) {
        float a0 = b2[j], a1 = b2[j + 1], a2 = b2[j + 2], a3 = b2[j + 3];
#pragma unroll
        for (int k = 0; k < 64; k++) {
            float4 w = *reinterpret_cast<const float4*>(&w2[k * 64 + j]);
            float t0 = t1[k];
            a0 += t0 * w.x; a1 += t0 * w.y; a2 += t0 * w.z; a3 += t0 * w.w;
        }
        atomicAdd(&aggp[j],     a0);
        atomicAdd(&aggp[j + 1], a1);
        atomicAdd(&aggp[j + 2], a2);
        atomicAdd(&aggp[j + 3], a3);
    }
}

__global__ __launch_bounds__(256) void edge_kernel_atomic(
    const float* __restrict__ edge_attr, const int* __restrict__ ei,
    const float* __restrict__ e1w1, const float* __restrict__ e1b1,
    const float* __restrict__ e1w2, const float* __restrict__ e1b2,
    const float* __restrict__ e2w1, const float* __restrict__ e2b1,
    const float* __restrict__ e2w2, const float* __restrict__ e2b2,
    float* __restrict__ agg1, float* __restrict__ agg2)
{
    __shared__ __align__(16) float sW[2 * 6272];
    for (int t = threadIdx.x; t < 2048; t += 256) sW[t]         = e1w1[t];
    for (int t = threadIdx.x; t < 64;   t += 256) sW[2048 + t]  = e1b1[t];
    for (int t = threadIdx.x; t < 4096; t += 256) sW[2112 + t]  = e1w2[t];
    for (int t = threadIdx.x; t < 64;   t += 256) sW[6208 + t]  = e1b2[t];
    for (int t = threadIdx.x; t < 2048; t += 256) sW[6272 + t]  = e2w1[t];
    for (int t = threadIdx.x; t < 64;   t += 256) sW[8320 + t]  = e2b1[t];
    for (int t = threadIdx.x; t < 4096; t += 256) sW[8384 + t]  = e2w2[t];
    for (int t = threadIdx.x; t < 64;   t += 256) sW[12480 + t] = e2b2[t];
    __syncthreads();

    int e = blockIdx.x * 256 + threadIdx.x;
    if (e >= E_) return;
    int tg = ei[E_ + e];

    float ea[32];
    {
        const float4* p = reinterpret_cast<const float4*>(edge_attr + (size_t)e * 32);
#pragma unroll
        for (int r = 0; r < 8; r++) {
            float4 v = p[r];
            ea[4 * r] = v.x; ea[4 * r + 1] = v.y; ea[4 * r + 2] = v.z; ea[4 * r + 3] = v.w;
        }
    }
    conv_atomic_1(&sW[0],    ea, agg1 + (size_t)tg * 64);
    conv_atomic_1(&sW[6272], ea, agg2 + (size_t)tg * 64);
}

// ===========================================================================
// Node update conv1 (in place over agg1); deg derived from rowptr.
// ===========================================================================
__global__ __launch_bounds__(256) void node1_kernel(
    const float* __restrict__ x, float* __restrict__ agg1,
    const int* __restrict__ rowptr,
    const float* __restrict__ n1w, const float* __restrict__ n1b)
{
    __shared__ __align__(16) float sA[4096], sB[4096], sb[64];
    for (int t = threadIdx.x; t < 4096; t += 256) { sA[t] = n1w[t]; sB[t] = n1w[4096 + t]; }
    if (threadIdx.x < 64) sb[threadIdx.x] = n1b[threadIdx.x];
    __syncthreads();

    int i = blockIdx.x * 256 + threadIdx.x;
    if (i >= N_) return;

    float xi[64], ag[64];
    {
        const float4* px = reinterpret_cast<const float4*>(x + (size_t)i * 64);
        const float4* pa = reinterpret_cast<const float4*>(agg1 + (size_t)i * 64);
#pragma unroll
        for (int r = 0; r < 16; r++) {
            float4 v = px[r];
            xi[4 * r] = v.x; xi[4 * r + 1] = v.y; xi[4 * r + 2] = v.z; xi[4 * r + 3] = v.w;
            float4 a = pa[r];
            ag[4 * r] = a.x; ag[4 * r + 1] = a.y; ag[4 * r + 2] = a.z; ag[4 * r + 3] = a.w;
        }
    }
    float d = (float)(rowptr[i + 1] - rowptr[i]);

#pragma unroll
    for (int j = 0; j < 64; j += 4) {
        float sx = sb[j], sy = sb[j + 1], sz = sb[j + 2], sw_ = sb[j + 3];
        float gx = 0.f, gy = 0.f, gz = 0.f, gw = 0.f;
#pragma unroll
        for (int k = 0; k < 64; k++) {
            float4 wa = *reinterpret_cast<const float4*>(&sA[k * 64 + j]);
            float xv = xi[k];
            sx += xv * wa.x; sy += xv * wa.y; sz += xv * wa.z; sw_ += xv * wa.w;
            float4 wb = *reinterpret_cast<const float4*>(&sB[k * 64 + j]);
            float av = ag[k];
            gx += av * wb.x; gy += av * wb.y; gz += av * wb.z; gw += av * wb.w;
        }
        float4 o;
        o.x = leaky(d * sx + gx);
        o.y = leaky(d * sy + gy);
        o.z = leaky(d * sz + gz);
        o.w = leaky(d * sw_ + gw);
        *reinterpret_cast<float4*>(&agg1[(size_t)i * 64 + j]) = o;
    }
}

// ===========================================================================
// Node update conv2 + heads (z/mu/logvar). No pooling atomics here.
// ===========================================================================
__global__ __launch_bounds__(256) void node2_kernel(
    const float* __restrict__ h1, const float* __restrict__ agg2,
    const int* __restrict__ rowptr,
    const float* __restrict__ n2w, const float* __restrict__ n2b,
    const float* __restrict__ mu_w, const float* __restrict__ mu_b,
    const float* __restrict__ lv_w, const float* __restrict__ lv_b,
    float* __restrict__ out)
{
    __shared__ __align__(16) float sA[4096], sB[4096], sb[64];
    __shared__ __align__(16) float sMu[2048], sLv[2048], sMb[32], sLb[32];
    for (int t = threadIdx.x; t < 4096; t += 256) { sA[t] = n2w[t]; sB[t] = n2w[4096 + t]; }
    for (int t = threadIdx.x; t < 2048; t += 256) { sMu[t] = mu_w[t]; sLv[t] = lv_w[t]; }
    if (threadIdx.x < 64) sb[threadIdx.x] = n2b[threadIdx.x];
    if (threadIdx.x < 32) { sMb[threadIdx.x] = mu_b[threadIdx.x]; sLb[threadIdx.x] = lv_b[threadIdx.x]; }
    __syncthreads();

    int i = blockIdx.x * 256 + threadIdx.x;
    if (i >= N_) return;

    float hi[64], ag[64];
    {
        const float4* ph = reinterpret_cast<const float4*>(h1 + (size_t)i * 64);
        const float4* pa = reinterpret_cast<const float4*>(agg2 + (size_t)i * 64);
#pragma unroll
        for (int r = 0; r < 16; r++) {
            float4 v = ph[r];
            hi[4 * r] = v.x; hi[4 * r + 1] = v.y; hi[4 * r + 2] = v.z; hi[4 * r + 3] = v.w;
            float4 a = pa[r];
            ag[4 * r] = a.x; ag[4 * r + 1] = a.y; ag[4 * r + 2] = a.z; ag[4 * r + 3] = a.w;
        }
    }
    float d = (float)(rowptr[i + 1] - rowptr[i]);

    float t2[64];
#pragma unroll
    for (int j = 0; j < 64; j += 4) {
        float sx = sb[j], sy = sb[j + 1], sz = sb[j + 2], sw_ = sb[j + 3];
        float gx = 0.f, gy = 0.f, gz = 0.f, gw = 0.f;
#pragma unroll
        for (int k = 0; k < 64; k++) {
            float4 wa = *reinterpret_cast<const float4*>(&sA[k * 64 + j]);
            float hv = hi[k];
            sx += hv * wa.x; sy += hv * wa.y; sz += hv * wa.z; sw_ += hv * wa.w;
            float4 wb = *reinterpret_cast<const float4*>(&sB[k * 64 + j]);
            float av = ag[k];
            gx += av * wb.x; gy += av * wb.y; gz += av * wb.z; gw += av * wb.w;
        }
        t2[j]     = leaky(d * sx + gx);
        t2[j + 1] = leaky(d * sy + gy);
        t2[j + 2] = leaky(d * sz + gz);
        t2[j + 3] = leaky(d * sw_ + gw);
    }

#pragma unroll
    for (int j = 0; j < 32; j += 4) {
        float ax = sMb[j], ay = sMb[j + 1], az = sMb[j + 2], aw = sMb[j + 3];
#pragma unroll
        for (int k = 0; k < 64; k++) {
            float4 w = *reinterpret_cast<const float4*>(&sMu[k * 32 + j]);
            float t = t2[k];
            ax += t * w.x; ay += t * w.y; az += t * w.z; aw += t * w.w;
        }
        float4 o; o.x = ax; o.y = ay; o.z = az; o.w = aw;
        *reinterpret_cast<float4*>(&out[(size_t)i * 32 + j]) = o;                    // z
        *reinterpret_cast<float4*>(&out[(size_t)N_ * 32 + (size_t)i * 32 + j]) = o;  // mu
    }
#pragma unroll
    for (int j = 0; j < 32; j += 4) {
        float ax = sLb[j], ay = sLb[j + 1], az = sLb[j + 2], aw = sLb[j + 3];
#pragma unroll
        for (int k = 0; k < 64; k++) {
            float4 w = *reinterpret_cast<const float4*>(&sLv[k * 32 + j]);
            float t = t2[k];
            ax += t * w.x; ay += t * w.y; az += t * w.z; aw += t * w.w;
        }
        float4 o; o.x = ax; o.y = ay; o.z = az; o.w = aw;
        *reinterpret_cast<float4*>(&out[2ull * N_ * 32 + (size_t)i * 32 + j]) = o;   // logvar
    }
}

// ===========================================================================
// Pool: block per graph; batch is sorted -> binary search range; block reduce.
// ===========================================================================
__global__ __launch_bounds__(256) void pool_kernel(
    const float* __restrict__ z, const int* __restrict__ batch,
    const float* __restrict__ cls_w, const float* __restrict__ cls_b,
    float* __restrict__ out)
{
    __shared__ int sLo, sHi;
    __shared__ float sred[256];
    __shared__ float pooled[32];
    int g = blockIdx.x;
    if (threadIdx.x == 0) {
        int lo = 0, hi = N_;
        while (lo < hi) { int m = (lo + hi) >> 1; if (batch[m] < g) lo = m + 1; else hi = m; }
        sLo = lo;
        int lo2 = lo; hi = N_;
        while (lo2 < hi) { int m = (lo2 + hi) >> 1; if (batch[m] < g + 1) lo2 = m + 1; else hi = m; }
        sHi = lo2;
    }
    __syncthreads();
    int lo = sLo, hi = sHi;
    int f = threadIdx.x & 31, r = threadIdx.x >> 5;
    float acc = 0.f;
    for (int i = lo + r; i < hi; i += 8) acc += z[(size_t)i * 32 + f];
    sred[threadIdx.x] = acc;
    __syncthreads();
    if (threadIdx.x < 128) sred[threadIdx.x] += sred[threadIdx.x + 128];
    __syncthreads();
    if (threadIdx.x < 64)  sred[threadIdx.x] += sred[threadIdx.x + 64];
    __syncthreads();
    if (threadIdx.x < 32) {
        float s = sred[threadIdx.x] + sred[threadIdx.x + 32];
        pooled[threadIdx.x] = s / fmaxf((float)(hi - lo), 1.0f);
    }
    __syncthreads();
    if (threadIdx.x < 10) {
        int j = threadIdx.x;
        float accj = cls_b[j];
#pragma unroll
        for (int k = 0; k < 32; k++) accj += pooled[k] * cls_w[k * 10 + j];
        out[3ull * N_ * 32 + (size_t)g * 10 + j] = accj;
    }
}

// ===========================================================================
extern "C" void kernel_launch(void* const* d_in, const int* in_sizes, int n_in,
                              void* d_out, int out_size, void* d_ws, size_t ws_size,
                              hipStream_t stream)
{
    const float* x         = (const float*)d_in[0];
    const int*   ei        = (const int*)  d_in[1];
    const float* edge_attr = (const float*)d_in[2];
    const int*   batch     = (const int*)  d_in[3];
    const float* e1w1 = (const float*)d_in[4];
    const float* e1b1 = (const float*)d_in[5];
    const float* e1w2 = (const float*)d_in[6];
    const float* e1b2 = (const float*)d_in[7];
    const float* n1w  = (const float*)d_in[8];
    const float* n1b  = (const float*)d_in[9];
    const float* e2w1 = (const float*)d_in[10];
    const float* e2b1 = (const float*)d_in[11];
    const float* e2w2 = (const float*)d_in[12];
    const float* e2b2 = (const float*)d_in[13];
    const float* n2w  = (const float*)d_in[14];
    const float* n2b  = (const float*)d_in[15];
    const float* mu_w = (const float*)d_in[16];
    const float* mu_b = (const float*)d_in[17];
    const float* lv_w = (const float*)d_in[18];
    const float* lv_b = (const float*)d_in[19];
    const float* cls_w = (const float*)d_in[20];
    const float* cls_b = (const float*)d_in[21];

    float* out = (float*)d_out;
    char*  wsb = (char*)d_ws;

    // ws layout (all 256B-aligned)
    size_t off = 0;
    auto alloc = [&](size_t bytes) { size_t o = off; off = (off + bytes + 255) & ~(size_t)255; return o; };
    int*   rowptr = (int*)  (wsb + alloc((N_ + 1) * sizeof(int)));
    int*   h      = (int*)  (wsb + alloc(N_ * sizeof(int)));
    int*   cursor = (int*)  (wsb + alloc(N_ * sizeof(int)));
    int*   eids   = (int*)  (wsb + alloc((size_t)E_ * sizeof(int)));
    int*   bsums  = (int*)  (wsb + alloc(512 * sizeof(int)));
    float* agg1   = (float*)(wsb + alloc((size_t)N_ * 64 * sizeof(float)));
    float* agg2   = (float*)(wsb + alloc((size_t)N_ * 64 * sizeof(float)));
    size_t fixed_end = off;

    // choose chunk count C from ws_size (deterministic -> graph-capture safe)
    int C = 0; size_t cap = 0;
    const int cands[6] = {1, 2, 4, 8, 16, 32};
    for (int ci = 0; ci < 6; ci++) {
        int c = cands[ci];
        size_t cp = (c == 1) ? (size_t)E_ : ((size_t)E_ / c + (size_t)E_ / (4 * c) + 2048);
        if (fixed_end + 2 * (cp * 64 * sizeof(float) + 256) <= ws_size) { C = c; cap = cp; break; }
    }
    float* emb1 = nullptr; float* emb2 = nullptr;
    if (C) {
        emb1 = (float*)(wsb + alloc(cap * 64 * sizeof(float)));
        emb2 = (float*)(wsb + alloc(cap * 64 * sizeof(float)));
    }

    const int nb = (N_ + 255) / 256;   // 391

    // CSR build (always: rowptr also provides deg for node kernels)
    hipMemsetAsync(h, 0, (size_t)N_ * sizeof(int), stream);
    hist_kernel<<<(E_ + 255) / 256, 256, 0, stream>>>(ei, h);
    scan1_kernel<<<nb, 256, 0, stream>>>(h, bsums);
    scan2_kernel<<<1, 512, 0, stream>>>(bsums, nb);
    scan3_kernel<<<nb, 256, 0, stream>>>(h, bsums, rowptr, cursor);

    if (C) {
        scatter_kernel<<<(E_ + 255) / 256, 256, 0, stream>>>(ei, cursor, eids);
        int NC = (N_ + C - 1) / C;
        for (int c = 0; c < C; c++) {
            int cs = c * NC;
            int ce = (cs + NC < N_) ? cs + NC : N_;
            mlp_chunk_kernel<<<(int)((cap + 255) / 256), 256, 0, stream>>>(
                edge_attr, eids, rowptr,
                e1w1, e1b1, e1w2, e1b2, e2w1, e2b1, e2w2, e2b2,
                emb1, emb2, cs, ce, (int)cap);
            gather_kernel<<<(NC + 3) / 4, 256, 0, stream>>>(
                rowptr, emb1, emb2, agg1, agg2, cs, ce);
        }
    } else {
        hipMemsetAsync(agg1, 0, 2ull * N_ * 64 * sizeof(float), stream);
        edge_kernel_atomic<<<(E_ + 255) / 256, 256, 0, stream>>>(
            edge_attr, ei, e1w1, e1b1, e1w2, e1b2, e2w1, e2b1, e2w2, e2b2, agg1, agg2);
    }

    node1_kernel<<<nb, 256, 0, stream>>>(x, agg1, rowptr, n1w, n1b);
    node2_kernel<<<nb, 256, 0, stream>>>(agg1, agg2, rowptr, n2w, n2b,
                                         mu_w, mu_b, lv_w, lv_b, out);
    pool_kernel<<<G_, 256, 0, stream>>>(out, batch, cls_w, cls_b, out);
}